// Round 1
// 389.294 us; speedup vs baseline: 1.0665x; 1.0665x over previous
//
#include <hip/hip_runtime.h>
#include <cstdint>

// ---------------------------------------------------------------------------
// dysOpt: Davis-Yin splitting, 262144 rows x 64 vars, dynamic T.
//
// x20 u-space iteration (U = 20*(z + C), CC = 20*C):
//   m'  = med3(U, CC, CC+20)      (= 20*(clamp(z,0,1)+C)), computed IN PLACE
//   U+  = K1*m' + nc[j]           (nc = -c, stored negated for pk_fma)
//   Sx  = 0.05*(Sm' - 64*CC) ; t = K2*Sx - R
//   corr20 = t*(20/64) - 10 ; R+ = R - Sx + 32 ; CC+ = K1*CC + corr20
// Exact algebra vs reference; rescale rounding ~1 ulp/iter damped by the
// K1 = 0.9975 contraction.
//
// ROUND-11 (VALU-issue attack; counters: MfmaUtil 0, HBM 4.6%, VALUBusy ~110):
//  * pass1/pass2 move to layout B: 1 lane = 1 row (64 elems/lane, 64 rows/
//    wave). Eliminates reduce4 (DPP + hazard nops) and amortizes the scalar
//    recurrence tail over 64 rows instead of 16.
//  * VOP3P packed f32: v_pk_add_f32 for the row partial sums, v_pk_fma_f32
//    for the U update. c is stored NEGATED (nc) so pk_fma needs no neg
//    modifier. Static count: 64 med3 + 32 pk_add + 32 pk_fma + ~10 tail
//    = ~138 instr/wave-iter for 64 rows = 2.17 instr/row-iter (was 3.94).
//  * __launch_bounds__(256,2): pinned U(64)+nc(64) + temps ~ 170 VGPR,
//    cap 256 -> no spill; 2 waves/SIMD suffice (pure-VALU, 64-wide ILP,
//    per-iter serial chain ~30cy << 276cy issue time).
//  * probe kernel kept BYTE-IDENTICAL to round-10 (layout A, scalar chk):
//    it is serial-depth-bound, and keeping its arithmetic frozen isolates
//    Ts semantics (any Ts <= T stays correct).
//
// Structure: probe (8192 rows, checked every iter) -> Ts = max Tr <= T;
// pass1: P = Ts-2 unchecked iters, then checked to wave all-pass = ib
// (residual monotone per row => ib = max(P+1, wave-max Tr) <= T, the argmax
// wave reports exactly T); checkpoint z(ib), atomicMax T.
// pass2: resume ib -> T, +1 differentiable step, clamp, store.
// Check (per row, fully in-lane in layout B):
//   400*||dz||^2 = q2 - 2*dCC*q1 + 64*dCC^2 <= 400*TOL^2 = 0.04.
// ---------------------------------------------------------------------------

#ifndef JAX_PARTITIONABLE
#define JAX_PARTITIONABLE 1
#endif

#define BATCHN 262144
#define MAXIT  200

// layout A (probe only): 16 rows/wave, 4 lanes/row, 16 elems/lane
#define RPW_A  16
#define PROBE_ROWS 8192
#define PROBE_WAVES (PROBE_ROWS / RPW_A)    // 512
#define NWAVES_A (BATCHN / RPW_A)           // 16384 (workspace offset compat)

// layout B (pass1/pass2): 64 rows/wave, 1 lane/row, 64 elems/lane
#define RPW_B  64
#define NWAVES_B (BATCHN / RPW_B)           // 4096

#define K1 0.9975f   // 1 - a^2
#define K2 1.9975f   // 2 - a^2

typedef float v2f __attribute__((ext_vector_type(2)));

// ---- packed f32 (VOP3P, full-rate on CDNA) --------------------------------
__device__ __forceinline__ v2f pk_add(v2f a, v2f b) {
  v2f d;
  asm("v_pk_add_f32 %0, %1, %2" : "=v"(d) : "v"(a), "v"(b));
  return d;
}
__device__ __forceinline__ v2f pk_fma(v2f a, v2f b, v2f c) {
  v2f d;
  asm("v_pk_fma_f32 %0, %1, %2, %3" : "=v"(d) : "v"(a), "v"(b), "v"(c));
  return d;
}

__device__ __forceinline__ void tf2x32(uint32_t x0, uint32_t x1,
                                       uint32_t& o0, uint32_t& o1) {
  const uint32_t k0 = 0u, k1 = 1u;                 // jax.random.key(1) -> [0,1]
  const uint32_t k2 = 0x1BD11BDAu ^ k0 ^ k1;
  x0 += k0; x1 += k1;
#define TFR(r) { x0 += x1; x1 = (x1 << (r)) | (x1 >> (32 - (r))); x1 ^= x0; }
  TFR(13) TFR(15) TFR(26) TFR(6)   x0 += k1; x1 += k2 + 1u;
  TFR(17) TFR(29) TFR(16) TFR(24)  x0 += k2; x1 += k0 + 2u;
  TFR(13) TFR(15) TFR(26) TFR(6)   x0 += k0; x1 += k1 + 3u;
  TFR(17) TFR(29) TFR(16) TFR(24)  x0 += k1; x1 += k2 + 4u;
  TFR(13) TFR(15) TFR(26) TFR(6)   x0 += k2; x1 += k0 + 5u;
#undef TFR
  o0 = x0; o1 = x1;
}

__device__ __forceinline__ float z0_at(uint32_t f) {
  uint32_t b;
#if JAX_PARTITIONABLE
  uint32_t o0, o1;
  tf2x32(0u, f, o0, o1);
  b = o0 ^ o1;
#else
  const uint32_t H = 8388608u;
  uint32_t lo = (f < H) ? f : (f - H);
  uint32_t o0, o1;
  tf2x32(lo, lo + H, o0, o1);
  b = (f < H) ? o0 : o1;
#endif
  return __uint_as_float((b >> 9) | 0x3f800000u) - 1.0f;
}

// ===========================================================================
// layout A helpers — used ONLY by the probe kernel (kept identical to r10)
// ===========================================================================

// DPP cross-lane add within a quad: v += v(lane DPP-selected). Pure VALU.
template <int CTRL>
__device__ __forceinline__ float dpp_add(float v) {
  int s = __builtin_amdgcn_mov_dpp(__float_as_int(v), CTRL, 0xF, 0xF, true);
  return v + __int_as_float(s);
}

// 4-lane row reduction (row = one quad), all-VALU
__device__ __forceinline__ float reduce4(float v) {
  v = dpp_add<0xB1>(v);    // quad_perm [1,0,3,2] : xor 1
  v = dpp_add<0x4E>(v);    // quad_perm [2,3,0,1] : xor 2
  return v;
}

// checked iteration (A): returns 400*||dz_row||^2 (replicated in the row)
__device__ __forceinline__ float chk_iter_A(float U[16], const float c[16],
                                            float& CC, float& R) {
  const float Ch = CC + 20.0f;
  float sp[4] = {0.0f, 0.0f, 0.0f, 0.0f};
  float q1a = 0.0f, q1b = 0.0f, q2a = 0.0f, q2b = 0.0f;
#pragma unroll
  for (int j = 0; j < 16; ++j) {
    float m = __builtin_amdgcn_fmed3f(U[j], CC, Ch);
    sp[j & 3] += m;
    float un = __builtin_fmaf(K1, m, -c[j]);
    float d = un - U[j];
    if (j & 1) { q1b += d; q2b = __builtin_fmaf(d, d, q2b); }
    else       { q1a += d; q2a = __builtin_fmaf(d, d, q2a); }
    U[j] = un;
  }
  float s = (sp[0] + sp[1]) + (sp[2] + sp[3]);
  s = reduce4(s);
  float Sx = 0.05f * __builtin_fmaf(-64.0f, CC, s);
  float t  = __builtin_fmaf(K2, Sx, -R);
  float corr20 = __builtin_fmaf(t, 0.3125f, -10.0f);
  R = (R - Sx) + 32.0f;
  float CCn = __builtin_fmaf(K1, CC, corr20);
  float dCC = CCn - CC;
  CC = CCn;
  float q1 = reduce4(q1a + q1b);
  float q2 = reduce4(q2a + q2b);
  // 400*ds = q2 - 2*dCC*q1 + 64*dCC^2
  float a = __builtin_fmaf(64.0f, dCC, -2.0f * q1);
  return __builtin_fmaf(dCC, a, q2);
}

__device__ __forceinline__ void load_c_A(const float* __restrict__ cost,
                                         int base, float c[16]) {
#pragma unroll
  for (int k = 0; k < 4; ++k) {
    const float4 cq = *(const float4*)(cost + base + 4 * k);
    c[4 * k + 0] = cq.x; c[4 * k + 1] = cq.y;
    c[4 * k + 2] = cq.z; c[4 * k + 3] = cq.w;
  }
}

// Pin value to a VGPR: asm-defined => compiler cannot remat via reload.
__device__ __forceinline__ void pin16(float v[16]) {
#pragma unroll
  for (int j = 0; j < 16; ++j) asm("" : "+v"(v[j]));
}

__device__ __forceinline__ void init_state_A(const float* __restrict__ cost,
                                             int base, float c[16],
                                             float U[16], float& CC,
                                             float& R) {
  load_c_A(cost, base, c);
  float r = 0.0f;
#pragma unroll
  for (int j = 0; j < 16; ++j) {
    float z0 = z0_at((uint32_t)(base + j));
    U[j] = 20.0f * z0;
    r = __builtin_fmaf(0.05f, c[j], r + z0);   // r += z0 + 0.05*c
  }
  pin16(c);
  pin16(U);
  R = reduce4(r);                               // R = Sz + a*Sc
  CC = 0.0f;
}

// --- probe: rows [0, PROBE_ROWS), checked every iter, atomicMax Ts ---------
__global__ __launch_bounds__(256, 4) void dys_probe(
    const float* __restrict__ cost, int* __restrict__ Tsample) {
  const int lane = threadIdx.x & 63;
  const int gw = blockIdx.x * 4 + (threadIdx.x >> 6);
  const int base = (gw * RPW_A + (lane >> 2)) * 64 + (lane & 3) * 16;

  float c[16], U[16], CC, R;
  init_state_A(cost, base, c, U, CC, R);

  int ib = MAXIT;
  for (int i = 1; i <= MAXIT; ++i) {
    float ds = chk_iter_A(U, c, CC, R);
    if (__all(ds <= 0.04f)) { ib = i; break; }   // wave-max Tr
  }
  if (lane == 0) atomicMax(Tsample, ib);
}

// ===========================================================================
// layout B helpers — 1 lane = 1 row; packed f32; no cross-lane ops
// ===========================================================================

__device__ __forceinline__ void pin32(v2f v[32]) {
#pragma unroll
  for (int j = 0; j < 32; ++j) asm("" : "+v"(v[j]));
}

// ~138 VALU/wave-iter for 64 rows: 64 med3 + 32 pk_add + 32 pk_fma + tail
__device__ __forceinline__ void fast_iter_B(v2f U2[32], const v2f nc2[32],
                                            float& CC, float& R) {
  const float Ch = CC + 20.0f;
  const v2f K1p = {K1, K1};
  v2f spA = {0.0f, 0.0f}, spB = {0.0f, 0.0f};
#pragma unroll
  for (int p = 0; p < 32; ++p) {
    v2f m2;
    m2.x = __builtin_amdgcn_fmed3f(U2[p].x, CC, Ch);
    m2.y = __builtin_amdgcn_fmed3f(U2[p].y, CC, Ch);
    if (p & 1) spB = pk_add(spB, m2);
    else       spA = pk_add(spA, m2);
    U2[p] = pk_fma(K1p, m2, nc2[p]);             // U+ = K1*m' - c
  }
  v2f spc = pk_add(spA, spB);
  float s = spc.x + spc.y;                       // Sm' over the row, in-lane
  float Sx = 0.05f * __builtin_fmaf(-64.0f, CC, s);
  float t  = __builtin_fmaf(K2, Sx, -R);
  float corr20 = __builtin_fmaf(t, 0.3125f, -10.0f);
  R = (R - Sx) + 32.0f;
  CC = __builtin_fmaf(K1, CC, corr20);
}

// checked iteration (B): per-lane ds for the lane's own row
__device__ __forceinline__ float chk_iter_B(v2f U2[32], const v2f nc2[32],
                                            float& CC, float& R) {
  const float Ch = CC + 20.0f;
  const v2f K1p = {K1, K1};
  v2f spA = {0.0f, 0.0f}, spB = {0.0f, 0.0f};
  v2f q1v = {0.0f, 0.0f}, q2v = {0.0f, 0.0f};
#pragma unroll
  for (int p = 0; p < 32; ++p) {
    v2f m2, un2, d2;
    m2.x = __builtin_amdgcn_fmed3f(U2[p].x, CC, Ch);
    m2.y = __builtin_amdgcn_fmed3f(U2[p].y, CC, Ch);
    if (p & 1) spB = pk_add(spB, m2);
    else       spA = pk_add(spA, m2);
    un2 = pk_fma(K1p, m2, nc2[p]);
    d2.x = un2.x - U2[p].x;
    d2.y = un2.y - U2[p].y;
    q1v = pk_add(q1v, d2);
    q2v = pk_fma(d2, d2, q2v);
    U2[p] = un2;
  }
  v2f spc = pk_add(spA, spB);
  float s = spc.x + spc.y;
  float Sx = 0.05f * __builtin_fmaf(-64.0f, CC, s);
  float t  = __builtin_fmaf(K2, Sx, -R);
  float corr20 = __builtin_fmaf(t, 0.3125f, -10.0f);
  R = (R - Sx) + 32.0f;
  float CCn = __builtin_fmaf(K1, CC, corr20);
  float dCC = CCn - CC;
  CC = CCn;
  float q1 = q1v.x + q1v.y;
  float q2 = q2v.x + q2v.y;
  float a = __builtin_fmaf(64.0f, dCC, -2.0f * q1);
  return __builtin_fmaf(dCC, a, q2);
}

__device__ __forceinline__ void init_state_B(const float* __restrict__ cost,
                                             int base, v2f nc2[32],
                                             v2f U2[32], float& CC,
                                             float& R) {
  // load c NEGATED (pk_fma takes +nc, no neg-modifier syntax needed)
#pragma unroll
  for (int k = 0; k < 16; ++k) {
    const float4 cq = *(const float4*)(cost + base + 4 * k);
    nc2[2 * k + 0].x = -cq.x; nc2[2 * k + 0].y = -cq.y;
    nc2[2 * k + 1].x = -cq.z; nc2[2 * k + 1].y = -cq.w;
  }
  float r0 = 0.0f, r1 = 0.0f;
#pragma unroll
  for (int p = 0; p < 32; ++p) {
    float za = z0_at((uint32_t)(base + 2 * p));
    float zb = z0_at((uint32_t)(base + 2 * p + 1));
    U2[p].x = 20.0f * za;
    U2[p].y = 20.0f * zb;
    r0 = __builtin_fmaf(-0.05f, nc2[p].x, r0 + za);  // r += z0 + 0.05*c
    r1 = __builtin_fmaf(-0.05f, nc2[p].y, r1 + zb);
  }
  pin32(nc2);
  pin32(U2);
  R = r0 + r1;                                   // R = Sz + a*Sc, in-lane
  CC = 0.0f;
}

// --- pass1: P unchecked iters, checked to wave all-pass; checkpoint --------
__global__ __launch_bounds__(256, 2) void dys_pass1(
    const float* __restrict__ cost, const int* __restrict__ Tsample,
    int* __restrict__ Tglob, int* __restrict__ TrArr,
    float* __restrict__ zst) {
  const int lane = threadIdx.x & 63;
  const int gw = blockIdx.x * 4 + (threadIdx.x >> 6);
  const int base = (gw * RPW_B + lane) * 64;     // lane owns one full row

  v2f nc2[32], U2[32];
  float CC, R;
  init_state_B(cost, base, nc2, U2, CC, R);

  const int Ts = *Tsample;                 // uniform
  const int P = (Ts > 2) ? (Ts - 2) : 0;   // P+1 <= Ts <= T

  for (int i = 0; i < P; ++i) fast_iter_B(U2, nc2, CC, R);

  int ib = MAXIT;
  for (int i = P + 1; i <= MAXIT; ++i) {
    float ds = chk_iter_B(U2, nc2, CC, R);
    if (__all(ds <= 0.04f)) { ib = i; break; }
  }
  // ib = max(P+1, wave-max Tr) <= T; the argmax wave reports exactly T.

  const float CC05 = 0.05f * CC;           // z = 0.05*U - 0.05*CC
#pragma unroll
  for (int k = 0; k < 16; ++k) {
    float4 zq;
    zq.x = __builtin_fmaf(0.05f, U2[2 * k + 0].x, -CC05);
    zq.y = __builtin_fmaf(0.05f, U2[2 * k + 0].y, -CC05);
    zq.z = __builtin_fmaf(0.05f, U2[2 * k + 1].x, -CC05);
    zq.w = __builtin_fmaf(0.05f, U2[2 * k + 1].y, -CC05);
    *(float4*)(zst + base + 4 * k) = zq;
  }
  if (lane == 0) {
    TrArr[gw] = ib;
    atomicMax(Tglob, ib);
  }
}

// --- pass2: resume ib -> T, +1 differentiable step, clamp, store -----------
__global__ __launch_bounds__(256, 2) void dys_pass2(
    const float* __restrict__ cost, const int* __restrict__ Tglob,
    const int* __restrict__ TrArr, const float* __restrict__ zst,
    float* __restrict__ out) {
  const int lane = threadIdx.x & 63;
  const int gw = blockIdx.x * 4 + (threadIdx.x >> 6);
  const int base = (gw * RPW_B + lane) * 64;

  v2f nc2[32], U2[32];
#pragma unroll
  for (int k = 0; k < 16; ++k) {
    const float4 cq = *(const float4*)(cost + base + 4 * k);
    nc2[2 * k + 0].x = -cq.x; nc2[2 * k + 0].y = -cq.y;
    nc2[2 * k + 1].x = -cq.z; nc2[2 * k + 1].y = -cq.w;
  }
  float r0 = 0.0f, r1 = 0.0f;
#pragma unroll
  for (int k = 0; k < 16; ++k) {
    const float4 zq = *(const float4*)(zst + base + 4 * k);
    U2[2 * k + 0].x = 20.0f * zq.x; U2[2 * k + 0].y = 20.0f * zq.y;
    U2[2 * k + 1].x = 20.0f * zq.z; U2[2 * k + 1].y = 20.0f * zq.w;
    r0 += (zq.x + zq.y);
    r1 += (zq.z + zq.w);
  }
#pragma unroll
  for (int p = 0; p < 32; ++p) {
    r0 = __builtin_fmaf(-0.05f, nc2[p].x, r0);   // += 0.05*c
    r1 = __builtin_fmaf(-0.05f, nc2[p].y, r1);
  }
  pin32(nc2);
  pin32(U2);
  float CC = 0.0f;
  float R = r0 + r1;                       // R = Sz + a*Sc (invariant)

  const int T = *Tglob;
  const int ib = TrArr[gw];                // wave-uniform

  // (T - ib) lockstep iters to z(T), +1 differentiable step
  for (int i = ib; i <= T; ++i) fast_iter_B(U2, nc2, CC, R);

  const float CC05 = 0.05f * CC;
#pragma unroll
  for (int k = 0; k < 16; ++k) {
    float4 o;
    o.x = __builtin_amdgcn_fmed3f(
        __builtin_fmaf(0.05f, U2[2 * k + 0].x, -CC05), 0.0f, 1.0f);
    o.y = __builtin_amdgcn_fmed3f(
        __builtin_fmaf(0.05f, U2[2 * k + 0].y, -CC05), 0.0f, 1.0f);
    o.z = __builtin_amdgcn_fmed3f(
        __builtin_fmaf(0.05f, U2[2 * k + 1].x, -CC05), 0.0f, 1.0f);
    o.w = __builtin_amdgcn_fmed3f(
        __builtin_fmaf(0.05f, U2[2 * k + 1].y, -CC05), 0.0f, 1.0f);
    *(float4*)(out + base + 4 * k) = o;
  }
}

extern "C" void kernel_launch(void* const* d_in, const int* in_sizes, int n_in,
                              void* d_out, int out_size, void* d_ws,
                              size_t ws_size, hipStream_t stream) {
  const float* cost = (const float*)d_in[0];
  float* out = (float*)d_out;

  // ws: [0..4) Tglob ; [4..8) Tsample ; [1024..) TrArr ; then z ckpt
  // (offsets kept from r10: TrArr region sized for 16384 ints, B uses 4096)
  int* Tglob   = (int*)d_ws;
  int* Tsample = (int*)d_ws + 1;
  const size_t TR_OFF = 1024;
  const size_t Z_OFF  = TR_OFF + (size_t)NWAVES_A * sizeof(int);  // 16B-aligned
  int*   TrArr = (int*)((char*)d_ws + TR_OFF);
  float* zst   = (float*)((char*)d_ws + Z_OFF);

  hipMemsetAsync(d_ws, 0, 8, stream);   // Tglob = Tsample = 0

  dim3 block(256);
  dys_probe<<<dim3(PROBE_WAVES / 4), block, 0, stream>>>(cost, Tsample);
  dys_pass1<<<dim3(NWAVES_B / 4), block, 0, stream>>>(cost, Tsample, Tglob,
                                                      TrArr, zst);
  dys_pass2<<<dim3(NWAVES_B / 4), block, 0, stream>>>(cost, Tglob, TrArr, zst,
                                                      out);
}